// Round 3
// baseline (80.643 us; speedup 1.0000x reference)
//
#include <hip/hip_runtime.h>
#include <stdint.h>

// TripletLoss on MI355X. E=8192, N=2048, K=8, L=16, top-400 of Gumbel-perturbed logw.
// Round 3: two dispatches. k_prep (32 blocks): per-edge bc + pos/neg flags.
// k_fused (1 block, 1024 thr): LDS linked lists -> pair enum -> LDS radix top-k
// (wave-0 shfl suffix-scan instead of serial bin walk) -> deterministic reduce.

#define E_CONST 8192
#define N_CONST 2048
#define K_CONST 8
#define L_CONST 16
#define MAXS 400
#define EPS_F 1e-9f
#define CAP 4096          // LDS candidate slots (observed M ~ 3k)
#define NEXT_MASK 0x3FFFu
#define NIL 0x3FFFu

struct Cand { float val; uint32_t pack; };

// ---- threefry2x32, key = jax.random.key(42), partitionable path (validated absmax 0.0) ----
__device__ __forceinline__ uint2 threefry2x32_42(uint32_t x0, uint32_t x1) {
    const uint32_t ks0 = 0u, ks1 = 42u;
    const uint32_t ks2 = ks0 ^ ks1 ^ 0x1BD11BDAu;
    const uint32_t ks[3] = {ks0, ks1, ks2};
    const int R[2][4] = {{13, 15, 26, 6}, {17, 29, 16, 24}};
    x0 += ks0; x1 += ks1;
#pragma unroll
    for (int g = 0; g < 5; ++g) {
        const int* r = R[g & 1];
#pragma unroll
        for (int q = 0; q < 4; ++q) {
            x0 += x1;
            x1 = (x1 << r[q]) | (x1 >> (32 - r[q]));
            x1 ^= x0;
        }
        x0 += ks[(g + 1) % 3];
        x1 += ks[(g + 2) % 3] + (uint32_t)(g + 1);
    }
    return make_uint2(x0, x1);
}

__device__ __forceinline__ float gumbel_at(uint32_t idx) {
    uint2 o = threefry2x32_42(0u, idx);
    uint32_t bits = o.x ^ o.y;
    float u = __uint_as_float((bits >> 9) | 0x3F800000u) - 1.0f;
    return -logf(-logf(u + EPS_F) + EPS_F);
}

__device__ __forceinline__ int row_argmax(const float* __restrict__ row) {
    float best = row[0]; int bi = 0;
#pragma unroll
    for (int k = 1; k < K_CONST; ++k) {
        float v = row[k];
        if (v > best) { best = v; bi = k; }  // first-max == jnp.argmax
    }
    return bi;
}

__device__ __forceinline__ uint32_t sortable_key(float f) {
    uint32_t b = __float_as_uint(f);
    return (b & 0x80000000u) ? ~b : (b | 0x80000000u);
}

// ---- kernel 1 (32 blocks x 256): per-edge bc + flags ----
__global__ void k_prep(const float* __restrict__ clusters, const int* __restrict__ edges,
                       const int* __restrict__ keypts,
                       float* __restrict__ bc, unsigned char* __restrict__ flags) {
    __shared__ uint32_t s_mask;
    int tid = threadIdx.x;
    if (tid == 0) s_mask = 0;
    __syncthreads();
    if (tid < L_CONST) {
        int n = keypts[tid];
        atomicOr(&s_mask, 1u << row_argmax(clusters + n * K_CONST));
    }
    __syncthreads();
    uint32_t m = s_mask;

    int e = blockIdx.x * blockDim.x + tid;  // grid == E exactly
    int e0 = edges[2 * e], e1 = edges[2 * e + 1];
    const float* r0 = clusters + e0 * K_CONST;
    const float* r1 = clusters + e1 * K_CONST;
    int c0 = row_argmax(r0);
    int c1 = row_argmax(r1);
    float s = 0.f;
#pragma unroll
    for (int k = 0; k < K_CONST; ++k) s += sqrtf(r0[k] * r1[k]);  // sequential, matches ref
    bc[e] = s;
    unsigned char f = 0;
    if (((m >> c0) & 1u) | ((m >> c1) & 1u)) f = (c0 == c1) ? 1 : 2;  // 1=pos, 2=neg
    flags[e] = f;
}

// ---- kernel 2 (1 block x 1024): lists + pairs + radix top-k + reduce ----
__global__ __launch_bounds__(1024) void k_fused(
    const float* __restrict__ probas, const int* __restrict__ edges,
    const float* __restrict__ bc, const unsigned char* __restrict__ flags,
    Cand* __restrict__ spill, int spill_cap, float* __restrict__ out) {

    __shared__ Cand s_cand[CAP];          // 32 KB
    __shared__ int s_head[N_CONST];       // 8 KB
    __shared__ uint16_t s_next[E_CONST];  // 16 KB: next(14b) | flag(2b)
    __shared__ int s_hist[256];
    __shared__ float s_wsum[16];
    __shared__ int s_wcnt[16];
    __shared__ int s_cnt;
    __shared__ uint32_t s_prefix;
    __shared__ int s_target;

    int tid = threadIdx.x;
    for (int i = tid; i < N_CONST; i += 1024) s_head[i] = -1;
    if (tid == 0) s_cnt = 0;
    __syncthreads();

    // phase 1: build per-anchor linked lists in LDS, pack each edge's flag into s_next
    const int2* ed2 = (const int2*)edges;
    int aReg[8]; int fReg[8];
#pragma unroll
    for (int it = 0; it < 8; ++it) {
        int e = tid + it * 1024;
        int2 p = ed2[e];
        int f = flags[e];
        aReg[it] = p.x; fReg[it] = f;
        int old = atomicExch(&s_head[p.x], e);
        uint32_t nx = (old < 0) ? NIL : (uint32_t)old;
        s_next[e] = (uint16_t)(nx | ((uint32_t)f << 14));
    }
    __syncthreads();

    // phase 2: enumerate same-anchor (pos, neg) pairs with w > 0
#pragma unroll
    for (int it = 0; it < 8; ++it) {
        if (fReg[it] != 1) continue;  // pos edges only
        int e = tid + it * 1024;
        float be = bc[e];
        int j = s_head[aReg[it]];
        while (j >= 0) {
            uint16_t r = s_next[j];
            if ((r >> 14) == 2) {  // neg edge, same anchor
                float w = 1.0f - 0.5f * (be + bc[j]);
                if (w > 0.0f) {
                    float val = logf(fmaxf(w, EPS_F)) + gumbel_at((uint32_t)e * E_CONST + (uint32_t)j);
                    uint32_t pk = ((uint32_t)e << 16) | (uint32_t)j;
                    int s = atomicAdd(&s_cnt, 1);
                    if (s < CAP) { s_cand[s].val = val; s_cand[s].pack = pk; }
                    else { int g = s - CAP; if (g < spill_cap) { spill[g].val = val; spill[g].pack = pk; } }
                }
            }
            uint32_t nx = r & NEXT_MASK;
            j = (nx == NIL) ? -1 : (int)nx;
        }
    }
    __syncthreads();

    int M = s_cnt;
    int Mr = M; if (Mr > CAP + spill_cap) Mr = CAP + spill_cap;

    // phase 3: 4-pass radix threshold; suffix scan + bin select done by wave 0, no serial walk
    uint32_t thr = 0;
    if (M > MAXS) {
        if (tid == 0) { s_prefix = 0; s_target = MAXS; }
        __syncthreads();
        for (int pass = 0; pass < 4; ++pass) {
            int shift = 24 - 8 * pass;
            if (tid < 256) s_hist[tid] = 0;
            __syncthreads();
            uint32_t pfx = s_prefix;
            for (int t = tid; t < Mr; t += 1024) {
                Cand c = (t < CAP) ? s_cand[t] : spill[t - CAP];
                uint32_t k = sortable_key(c.val);
                if (pass == 0 || (k >> (shift + 8)) == pfx)
                    atomicAdd(&s_hist[(k >> shift) & 255], 1);
            }
            __syncthreads();
            if (tid < 64) {  // wave 0: lane L owns bins 4L..4L+3
                int h0 = s_hist[4 * tid], h1 = s_hist[4 * tid + 1];
                int h2 = s_hist[4 * tid + 2], h3 = s_hist[4 * tid + 3];
                int sincl = h0 + h1 + h2 + h3;
#pragma unroll
                for (int off = 1; off < 64; off <<= 1) {
                    int v = __shfl_down(sincl, off);
                    if (tid + off < 64) sincl += v;
                }
                int excl = __shfl_down(sincl, 1);   // suffix of lanes > L
                if (tid == 63) excl = 0;
                int suf3 = excl + h3;
                int suf2 = suf3 + h2;
                int suf1 = suf2 + h1;
                int suf0 = suf1 + h0;
                int tgt = s_target;            // lockstep read before any write
                uint32_t pfxOld = s_prefix;
                if      (suf0 >= tgt && suf1 < tgt) { s_prefix = (pfxOld << 8) | (4u*tid+0); s_target = tgt - suf1; }
                else if (suf1 >= tgt && suf2 < tgt) { s_prefix = (pfxOld << 8) | (4u*tid+1); s_target = tgt - suf2; }
                else if (suf2 >= tgt && suf3 < tgt) { s_prefix = (pfxOld << 8) | (4u*tid+2); s_target = tgt - suf3; }
                else if (suf3 >= tgt && excl < tgt) { s_prefix = (pfxOld << 8) | (4u*tid+3); s_target = tgt - excl; }
            }
            __syncthreads();
        }
        thr = s_prefix;  // exact sortable key of the 400th-largest value
    }

    // phase 4: sum selected terms, deterministic reduction
    float mysum = 0.f;
    int myc = 0;
    for (int t = tid; t < Mr; t += 1024) {
        Cand c = (t < CAP) ? s_cand[t] : spill[t - CAP];
        if (sortable_key(c.val) >= thr) {
            int i = (int)(c.pack >> 16), j = (int)(c.pack & 0xFFFFu);
            float pi = probas[i], pj = probas[j];
            mysum += logf(pi / (pi + pj));
            myc++;
        }
    }
#pragma unroll
    for (int off = 32; off > 0; off >>= 1) {
        mysum += __shfl_down(mysum, off);
        myc   += __shfl_down(myc, off);
    }
    int wid = tid >> 6;
    if ((tid & 63) == 0) { s_wsum[wid] = mysum; s_wcnt[wid] = myc; }
    __syncthreads();
    if (tid == 0) {
        float s = 0.f; int c = 0;
        for (int w = 0; w < 16; ++w) { s += s_wsum[w]; c += s_wcnt[w]; }
        if (c < 1) c = 1;
        out[0] = -s / (float)c;
    }
}

extern "C" void kernel_launch(void* const* d_in, const int* in_sizes, int n_in,
                              void* d_out, int out_size, void* d_ws, size_t ws_size,
                              hipStream_t stream) {
    const float* probas   = (const float*)d_in[0];
    const float* clusters = (const float*)d_in[1];
    const int*   edges    = (const int*)d_in[2];
    const int*   keypts   = (const int*)d_in[3];
    float* out = (float*)d_out;

    char* ws = (char*)d_ws;
    float*         bc    = (float*)(ws);                    // 32768 B
    unsigned char* flags = (unsigned char*)(ws + 32768);    // 8192 B
    Cand*          spill = (Cand*)(ws + 40960);
    int spill_cap = (int)((ws_size > 40960) ? (ws_size - 40960) / sizeof(Cand) : 0);
    if (spill_cap > (1 << 18)) spill_cap = 1 << 18;

    k_prep <<<E_CONST / 256, 256, 0, stream>>>(clusters, edges, keypts, bc, flags);
    k_fused<<<1, 1024, 0, stream>>>(probas, edges, bc, flags, spill, spill_cap, out);
}

// Round 4
// 33.344 us; speedup vs baseline: 2.4185x; 2.4185x over previous
//
#include <hip/hip_runtime.h>
#include <stdint.h>

// TripletLoss on MI355X. E=8192, N=2048, K=8, L=16, top-400 of Gumbel-perturbed logw.
// Round 4: dense pair enumeration. k_prep (32 blk): bc+flags. k_scanfill (1 blk):
// per-anchor CSR + pair-count scan + pair->anchor table. k_pairs (32 blk): one
// thread per valid pair, no atomics, coalesced cand writes. k_topk (1 blk): 4-pass
// radix threshold (wave-0 shfl suffix scan) + deterministic reduce.

#define E_CONST 8192
#define N_CONST 2048
#define K_CONST 8
#define L_CONST 16
#define MAXS 400
#define EPS_F 1e-9f

struct Cand { float val; uint32_t pack; };

// ---- threefry2x32, key = jax.random.key(42), partitionable path (validated absmax 0.0) ----
__device__ __forceinline__ uint2 threefry2x32_42(uint32_t x0, uint32_t x1) {
    const uint32_t ks0 = 0u, ks1 = 42u;
    const uint32_t ks2 = ks0 ^ ks1 ^ 0x1BD11BDAu;
    const uint32_t ks[3] = {ks0, ks1, ks2};
    const int R[2][4] = {{13, 15, 26, 6}, {17, 29, 16, 24}};
    x0 += ks0; x1 += ks1;
#pragma unroll
    for (int g = 0; g < 5; ++g) {
        const int* r = R[g & 1];
#pragma unroll
        for (int q = 0; q < 4; ++q) {
            x0 += x1;
            x1 = (x1 << r[q]) | (x1 >> (32 - r[q]));
            x1 ^= x0;
        }
        x0 += ks[(g + 1) % 3];
        x1 += ks[(g + 2) % 3] + (uint32_t)(g + 1);
    }
    return make_uint2(x0, x1);
}

__device__ __forceinline__ float gumbel_at(uint32_t idx) {
    uint2 o = threefry2x32_42(0u, idx);
    uint32_t bits = o.x ^ o.y;
    float u = __uint_as_float((bits >> 9) | 0x3F800000u) - 1.0f;
    return -logf(-logf(u + EPS_F) + EPS_F);
}

__device__ __forceinline__ int row_argmax(const float* __restrict__ row) {
    float best = row[0]; int bi = 0;
#pragma unroll
    for (int k = 1; k < K_CONST; ++k) {
        float v = row[k];
        if (v > best) { best = v; bi = k; }  // first-max == jnp.argmax
    }
    return bi;
}

__device__ __forceinline__ uint32_t sortable_key(float f) {
    uint32_t b = __float_as_uint(f);
    return (b & 0x80000000u) ? ~b : (b | 0x80000000u);
}

// ---- kernel 1 (32 blocks x 256): per-edge bc + flags ----
__global__ void k_prep(const float* __restrict__ clusters, const int* __restrict__ edges,
                       const int* __restrict__ keypts,
                       float* __restrict__ bc, unsigned char* __restrict__ flags) {
    __shared__ uint32_t s_mask;
    int tid = threadIdx.x;
    if (tid == 0) s_mask = 0;
    __syncthreads();
    if (tid < L_CONST) {
        int n = keypts[tid];
        atomicOr(&s_mask, 1u << row_argmax(clusters + n * K_CONST));
    }
    __syncthreads();
    uint32_t m = s_mask;

    int e = blockIdx.x * blockDim.x + tid;  // grid == E exactly
    int e0 = edges[2 * e], e1 = edges[2 * e + 1];
    const float* r0 = clusters + e0 * K_CONST;
    const float* r1 = clusters + e1 * K_CONST;
    int c0 = row_argmax(r0);
    int c1 = row_argmax(r1);
    float s = 0.f;
#pragma unroll
    for (int k = 0; k < K_CONST; ++k) s += sqrtf(r0[k] * r1[k]);  // sequential, matches ref
    bc[e] = s;
    unsigned char f = 0;
    if (((m >> c0) & 1u) | ((m >> c1) & 1u)) f = (c0 == c1) ? 1 : 2;  // 1=pos, 2=neg
    flags[e] = f;
}

// exclusive scan of 2048 ints (optionally elementwise product of two arrays) with 1024 threads
__device__ __forceinline__ void scan2048(const int* src0, const int* src1,
                                         int* dst, int* tmp, int* totalOut) {
    int tid = threadIdx.x;
    int lane = tid & 63, wid = tid >> 6;
    int i0 = 2 * tid, i1 = i0 + 1;
    int v0 = src1 ? src0[i0] * src1[i0] : src0[i0];
    int v1 = src1 ? src0[i1] * src1[i1] : src0[i1];
    int s = v0 + v1;
    int inc = s;
#pragma unroll
    for (int off = 1; off < 64; off <<= 1) {
        int u = __shfl_up(inc, off);
        if (lane >= off) inc += u;
    }
    if (lane == 63) tmp[wid] = inc;
    __syncthreads();
    if (wid == 0) {
        int w = (lane < 16) ? tmp[lane] : 0;
        int incw = w;
#pragma unroll
        for (int off = 1; off < 16; off <<= 1) {
            int u = __shfl_up(incw, off);
            if (lane >= off) incw += u;
        }
        if (lane < 16) tmp[lane] = incw - w;  // exclusive wave bases
    }
    __syncthreads();
    int base = tmp[wid] + (inc - s);
    dst[i0] = base;
    dst[i1] = base + v0;
    if (tid == 1023) *totalOut = base + v0 + v1;
    __syncthreads();
}

// ---- kernel 2 (1 block x 1024): CSR + scans + pair->anchor table ----
__global__ __launch_bounds__(1024) void k_scanfill(
    const int* __restrict__ edges, const unsigned char* __restrict__ flags,
    int* __restrict__ gBaseP, int* __restrict__ gBaseN, int* __restrict__ gBaseQ,
    uint16_t* __restrict__ posCSR, uint16_t* __restrict__ negCSR,
    uint16_t* __restrict__ pairAnchor, int pmax) {

    __shared__ int cntP[N_CONST], cntN[N_CONST];
    __shared__ int baseP[N_CONST], baseN[N_CONST], baseQ[N_CONST];
    __shared__ int tmp[16];
    __shared__ int totals[3];

    int tid = threadIdx.x;
    for (int i = tid; i < N_CONST; i += 1024) { cntP[i] = 0; cntN[i] = 0; }
    __syncthreads();

    // count
    const int2* ed2 = (const int2*)edges;
    int aReg[8]; int fReg[8];
#pragma unroll
    for (int it = 0; it < 8; ++it) {
        int e = tid + it * 1024;
        aReg[it] = ed2[e].x;
        fReg[it] = flags[e];
        if (fReg[it] == 1) atomicAdd(&cntP[aReg[it]], 1);
        else if (fReg[it] == 2) atomicAdd(&cntN[aReg[it]], 1);
    }
    __syncthreads();

    scan2048(cntP, 0,    baseP, tmp, &totals[0]);
    scan2048(cntN, 0,    baseN, tmp, &totals[1]);
    scan2048(cntP, cntN, baseQ, tmp, &totals[2]);

    // pair -> anchor table (cntP/cntN still hold counts)
    for (int a = tid; a < N_CONST; a += 1024) {
        int q = baseQ[a];
        int cnt = cntP[a] * cntN[a];
        for (int k = 0; k < cnt; ++k) {
            int t = q + k;
            if (t < pmax) pairAnchor[t] = (uint16_t)a;
        }
    }
    // bases to global
    for (int i = tid; i < N_CONST; i += 1024) {
        gBaseP[i] = baseP[i]; gBaseN[i] = baseN[i]; gBaseQ[i] = baseQ[i];
    }
    if (tid == 0) {
        gBaseP[N_CONST] = totals[0];
        gBaseN[N_CONST] = totals[1];
        gBaseQ[N_CONST] = totals[2];
    }
    // counts -> cursors
    for (int a = tid; a < N_CONST; a += 1024) { cntP[a] = baseP[a]; cntN[a] = baseN[a]; }
    __syncthreads();
    // CSR fill
#pragma unroll
    for (int it = 0; it < 8; ++it) {
        int e = tid + it * 1024;
        if (fReg[it] == 1)      { int s = atomicAdd(&cntP[aReg[it]], 1); posCSR[s] = (uint16_t)e; }
        else if (fReg[it] == 2) { int s = atomicAdd(&cntN[aReg[it]], 1); negCSR[s] = (uint16_t)e; }
    }
}

// ---- kernel 3 (32 blocks x 256): one thread per valid pair ----
__global__ void k_pairs(const float* __restrict__ bc,
                        const int* __restrict__ gBaseP, const int* __restrict__ gBaseN,
                        const int* __restrict__ gBaseQ,
                        const uint16_t* __restrict__ posCSR, const uint16_t* __restrict__ negCSR,
                        const uint16_t* __restrict__ pairAnchor, int pmax,
                        Cand* __restrict__ cand) {
    int P = gBaseQ[N_CONST];
    if (P > pmax) P = pmax;
    int stride = gridDim.x * blockDim.x;
    for (int t = blockIdx.x * blockDim.x + threadIdx.x; t < P; t += stride) {
        int a  = pairAnchor[t];
        int loc = t - gBaseQ[a];
        int nB = gBaseN[a], nn = gBaseN[a + 1] - nB;
        int ip = loc / nn;
        int jn = loc - ip * nn;
        int i = posCSR[gBaseP[a] + ip];
        int j = negCSR[nB + jn];
        float w = 1.0f - 0.5f * (bc[i] + bc[j]);
        float val;
        if (w > 0.0f)
            val = logf(fmaxf(w, EPS_F)) + gumbel_at((uint32_t)i * E_CONST + (uint32_t)j);
        else
            val = -INFINITY;  // ref: logw=-inf -> excluded via ok mask
        cand[t].val = val;
        cand[t].pack = ((uint32_t)i << 16) | (uint32_t)j;
    }
}

// ---- kernel 4 (1 block x 1024): radix threshold + reduce ----
__global__ __launch_bounds__(1024) void k_topk(
    const float* __restrict__ probas, const int* __restrict__ gBaseQ,
    const Cand* __restrict__ cand, int pmax, float* __restrict__ out) {
    __shared__ int s_hist[256];
    __shared__ float s_wsum[16];
    __shared__ int s_wcnt[16];
    __shared__ uint32_t s_prefix;
    __shared__ int s_target;

    int tid = threadIdx.x;
    int P = gBaseQ[N_CONST];
    int M = (P > pmax) ? pmax : P;

    uint32_t thr = 0;
    if (M > MAXS) {
        if (tid == 0) { s_prefix = 0; s_target = MAXS; }
        __syncthreads();
        for (int pass = 0; pass < 4; ++pass) {
            int shift = 24 - 8 * pass;
            if (tid < 256) s_hist[tid] = 0;
            __syncthreads();
            uint32_t pfx = s_prefix;
            for (int t = tid; t < M; t += 1024) {
                uint32_t k = sortable_key(cand[t].val);
                if (pass == 0 || (k >> (shift + 8)) == pfx)
                    atomicAdd(&s_hist[(k >> shift) & 255], 1);
            }
            __syncthreads();
            if (tid < 64) {  // wave 0: lane L owns bins 4L..4L+3, suffix-scan select
                int h0 = s_hist[4 * tid], h1 = s_hist[4 * tid + 1];
                int h2 = s_hist[4 * tid + 2], h3 = s_hist[4 * tid + 3];
                int sincl = h0 + h1 + h2 + h3;
#pragma unroll
                for (int off = 1; off < 64; off <<= 1) {
                    int v = __shfl_down(sincl, off);
                    if (tid + off < 64) sincl += v;
                }
                int excl = __shfl_down(sincl, 1);
                if (tid == 63) excl = 0;
                int suf3 = excl + h3;
                int suf2 = suf3 + h2;
                int suf1 = suf2 + h1;
                int suf0 = suf1 + h0;
                int tgt = s_target;
                uint32_t pfxOld = s_prefix;
                if      (suf0 >= tgt && suf1 < tgt) { s_prefix = (pfxOld << 8) | (4u*tid+0); s_target = tgt - suf1; }
                else if (suf1 >= tgt && suf2 < tgt) { s_prefix = (pfxOld << 8) | (4u*tid+1); s_target = tgt - suf2; }
                else if (suf2 >= tgt && suf3 < tgt) { s_prefix = (pfxOld << 8) | (4u*tid+2); s_target = tgt - suf3; }
                else if (suf3 >= tgt && excl < tgt) { s_prefix = (pfxOld << 8) | (4u*tid+3); s_target = tgt - excl; }
            }
            __syncthreads();
        }
        thr = s_prefix;  // exact sortable key of the 400th-largest value
    }

    float mysum = 0.f;
    int myc = 0;
    for (int t = tid; t < M; t += 1024) {
        Cand c = cand[t];
        if (c.val != -INFINITY && sortable_key(c.val) >= thr) {
            int i = (int)(c.pack >> 16), j = (int)(c.pack & 0xFFFFu);
            float pi = probas[i], pj = probas[j];
            mysum += logf(pi / (pi + pj));
            myc++;
        }
    }
#pragma unroll
    for (int off = 32; off > 0; off >>= 1) {
        mysum += __shfl_down(mysum, off);
        myc   += __shfl_down(myc, off);
    }
    int wid = tid >> 6;
    if ((tid & 63) == 0) { s_wsum[wid] = mysum; s_wcnt[wid] = myc; }
    __syncthreads();
    if (tid == 0) {
        float s = 0.f; int c = 0;
        for (int w = 0; w < 16; ++w) { s += s_wsum[w]; c += s_wcnt[w]; }
        if (c < 1) c = 1;
        out[0] = -s / (float)c;
    }
}

extern "C" void kernel_launch(void* const* d_in, const int* in_sizes, int n_in,
                              void* d_out, int out_size, void* d_ws, size_t ws_size,
                              hipStream_t stream) {
    const float* probas   = (const float*)d_in[0];
    const float* clusters = (const float*)d_in[1];
    const int*   edges    = (const int*)d_in[2];
    const int*   keypts   = (const int*)d_in[3];
    float* out = (float*)d_out;

    char* ws = (char*)d_ws;
    float*         bc     = (float*)(ws);                  // 32768
    unsigned char* flags  = (unsigned char*)(ws + 32768);  // 8192
    int*           gBaseP = (int*)(ws + 40960);            // (N+1)*4 -> reserve 8448
    int*           gBaseN = (int*)(ws + 49408);
    int*           gBaseQ = (int*)(ws + 57856);
    uint16_t*      posCSR = (uint16_t*)(ws + 66304);       // 16384
    uint16_t*      negCSR = (uint16_t*)(ws + 82688);       // 16384
    uint16_t*      pairAnchor = (uint16_t*)(ws + 99072);

    long long avail = (long long)ws_size - 99072 - 256;
    int pmax = (avail > 0) ? (int)(avail / 10) : 0;  // 2B pairAnchor + 8B cand per entry
    if (pmax > 65536) pmax = 65536;
    size_t cand_off = (size_t)(99072 + 2 * pmax + 7) & ~(size_t)7;
    Cand* cand = (Cand*)(ws + cand_off);

    k_prep    <<<E_CONST / 256, 256, 0, stream>>>(clusters, edges, keypts, bc, flags);
    k_scanfill<<<1, 1024, 0, stream>>>(edges, flags, gBaseP, gBaseN, gBaseQ,
                                       posCSR, negCSR, pairAnchor, pmax);
    k_pairs   <<<32, 256, 0, stream>>>(bc, gBaseP, gBaseN, gBaseQ, posCSR, negCSR,
                                       pairAnchor, pmax, cand);
    k_topk    <<<1, 1024, 0, stream>>>(probas, gBaseQ, cand, pmax, out);
}